// Round 6
// baseline (1322.129 us; speedup 1.0000x reference)
//
#include <hip/hip_runtime.h>
#include <stdint.h>

#define T_STEPS 100
#define D_IN 16
#define H_DIM 32
#define HD 50
#define KXH 48
#define EULER 10
#define STEPF 0.1f
#define DT_SCALERF (1.0f/24.0f)
#define TANH_SCALE 2.8853900817779268f   // 2*log2(e), folded into W1/W2/W3 + biases

typedef __attribute__((ext_vector_type(8))) short short8;
typedef __attribute__((ext_vector_type(4))) float float4v;
typedef __attribute__((ext_vector_type(4))) uint32_t uint4v;

// input prescaled by 2*log2(e): tanh(u) = 1 - 2/(exp2(us)+1)
__device__ __forceinline__ float tanh_pre(float us) {
    float e = __builtin_amdgcn_exp2f(us);
    return 1.0f - 2.0f * __builtin_amdgcn_rcpf(e + 1.0f);
}
__device__ __forceinline__ uint32_t f2bf_u(float f) {
    uint32_t u = __builtin_bit_cast(uint32_t, f);
    return u + 0x7fffu + ((u >> 16) & 1u);   // RNE
}
__device__ __forceinline__ uint32_t pack2(float lo, float hi) {
    return __builtin_amdgcn_perm(f2bf_u(hi), f2bf_u(lo), 0x07060302u);
}
__device__ __forceinline__ short f2bf(float f) { return (short)(f2bf_u(f) >> 16); }
__device__ __forceinline__ uint32_t bperm(int byte_addr, uint32_t v) {
    return (uint32_t)__builtin_amdgcn_ds_bpermute(byte_addr, (int)v);
}

// One fully self-contained wave per 16-batch chain. Zero LDS, zero barriers.
// Transposed formulation: weights = A-frags (constant in regs), activations =
// B-frags with batch in lane&15. The C-layout -> B-frag feature transpose is
// done in-register with ds_bpermute:
//   dest dword w of dest lane (q,n) = pack2 of C-regs (2w%4, +1) of tile
//   mt = (2T + (q>>1)) taken from src lane ((q&1)*2 + (w>>1))*16 + n.
// => per dest dword: 2 bpermutes (tile pair) + 1 cndmask by q>>1.
__global__ __launch_bounds__(64) void latode_kernel(
    const float* __restrict__ dt, const float* __restrict__ x,
    const float* __restrict__ W1, const float* __restrict__ b1,
    const float* __restrict__ W2, const float* __restrict__ b2,
    const float* __restrict__ W3, const float* __restrict__ b3,
    const float* __restrict__ W4, const float* __restrict__ b4,
    float* __restrict__ out)
{
    const int lane = threadIdx.x;
    const int n16  = lane & 15;       // batch column
    const int quad = lane >> 4;
    const int b0   = blockIdx.x * 16;

    // bpermute byte addresses (constant per lane):
    const int a_lo = ((((quad & 1) << 1) * 16) + n16) << 2;  // src quad 2*(q&1)
    const int a_hi = a_lo + 64;                              // src quad 2*(q&1)+1

    // ---- constant weight A-frags (bf16, prescaled by 2*log2e) ----
    short8 w1f[4][2];
#pragma unroll
    for (int mt = 0; mt < 4; ++mt) {
        int m = mt * 16 + n16;
#pragma unroll
        for (int kt = 0; kt < 2; ++kt)
#pragma unroll
            for (int j = 0; j < 8; ++j) {
                int kk = kt * 32 + quad * 8 + j;   // K remap: [h(0..31)|x(32..47)|pad]
                float w = 0.0f;
                if (m < HD) {
                    if (kk < 32)      w = W1[m * KXH + 16 + kk];
                    else if (kk < 48) w = W1[m * KXH + (kk - 32)];
                }
                w1f[mt][kt][j] = f2bf(w * TANH_SCALE);
            }
    }
    short8 w2f[2][2];
#pragma unroll
    for (int mt = 0; mt < 2; ++mt) {
        int m = mt * 16 + n16;
#pragma unroll
        for (int kt = 0; kt < 2; ++kt)
#pragma unroll
            for (int j = 0; j < 8; ++j) {
                int kk = kt * 32 + quad * 8 + j;
                w2f[mt][kt][j] = f2bf(kk < HD ? W2[m * HD + kk] * TANH_SCALE : 0.0f);
            }
    }
    short8 w3f[4];
#pragma unroll
    for (int mt = 0; mt < 4; ++mt) {
        int m = mt * 16 + n16;
#pragma unroll
        for (int j = 0; j < 8; ++j)
            w3f[mt][j] = f2bf(W3[m * H_DIM + quad * 8 + j] * TANH_SCALE);
    }
    float4v b1v[4], b3v[4], w4v[4], b2v[2];
#pragma unroll
    for (int mt = 0; mt < 4; ++mt)
#pragma unroll
        for (int r = 0; r < 4; ++r) {
            int f = mt * 16 + quad * 4 + r;
            b1v[mt][r] = (f < HD) ? b1[f] * TANH_SCALE : 0.0f;
            b3v[mt][r] = b3[f] * TANH_SCALE;
            w4v[mt][r] = W4[f];
        }
#pragma unroll
    for (int mt = 0; mt < 2; ++mt)
#pragma unroll
        for (int r = 0; r < 4; ++r)
            b2v[mt][r] = b2[mt * 16 + quad * 4 + r] * TANH_SCALE;
    const float b4s = b4[0];

    // h state fp32 C-layout: hC[mt][r] = h[feat mt*16+quad*4+r][batch n16]
    float4v hC[2];
    hC[0] = (float4v){0.f, 0.f, 0.f, 0.f};
    hC[1] = (float4v){0.f, 0.f, 0.f, 0.f};

    const float* xrow = x + (size_t)(b0 + n16) * (T_STEPS * D_IN);
    const float* drow = dt + (size_t)(b0 + n16) * (T_STEPS * 2);
    float4 xa = {0,0,0,0}, xb = {0,0,0,0};
    if (quad < 2) {
        xa = *(const float4*)(xrow + quad * 8);
        xb = *(const float4*)(xrow + quad * 8 + 4);
    }
    float2 dtv = *(const float2*)(drow);

#pragma unroll 1
    for (int t = 0; t < T_STEPS; ++t) {
        // x B-frag (k' 32..63: quads 0/1 carry x, quads 2/3 zero)
        short8 xB = (short8){0,0,0,0,0,0,0,0};
        if (quad < 2) {
            uint4v xp;
            xp[0] = pack2(xa.x, xa.y); xp[1] = pack2(xa.z, xa.w);
            xp[2] = pack2(xb.x, xb.y); xp[3] = pack2(xb.z, xb.w);
            xB = __builtin_bit_cast(short8, xp);
        }
        const float scl = (dtv.y - dtv.x) * DT_SCALERF;
        const float s10 = STEPF * scl;
        const float y0  = __shfl(xa.x, n16, 64);   // x[b0+n16][t,0]

        { // prefetch t+1
            int tn = (t + 1 < T_STEPS) ? t + 1 : (T_STEPS - 1);
            if (quad < 2) {
                xa = *(const float4*)(xrow + tn * D_IN + quad * 8);
                xb = *(const float4*)(xrow + tn * D_IN + quad * 8 + 4);
            }
            dtv = *(const float2*)(drow + tn * 2);
        }

        float psum = 0.0f;   // dy partial, accumulated over Euler steps

#pragma unroll 2
        for (int e = 0; e < EULER; ++e) {
            // ---- h: C-layout -> B-frag, in-register (4 pack + 8 bperm + 4 sel) ----
            uint32_t hp00 = pack2(hC[0][0], hC[0][1]);
            uint32_t hp01 = pack2(hC[0][2], hC[0][3]);
            uint32_t hp10 = pack2(hC[1][0], hC[1][1]);
            uint32_t hp11 = pack2(hC[1][2], hC[1][3]);
            uint4v hd;
            hd[0] = quad < 2 ? bperm(a_lo, hp00) : bperm(a_lo, hp10);
            hd[1] = quad < 2 ? bperm(a_lo, hp01) : bperm(a_lo, hp11);
            hd[2] = quad < 2 ? bperm(a_hi, hp00) : bperm(a_hi, hp10);
            hd[3] = quad < 2 ? bperm(a_hi, hp01) : bperm(a_hi, hp11);
            short8 hB = __builtin_bit_cast(short8, hd);

            // ---- u1 (8 MFMA) and u3 (4 MFMA) off the same hB ----
            float4v a1[4], a3[4];
#pragma unroll
            for (int mt = 0; mt < 4; ++mt) {
                a1[mt] = b1v[mt];
                a1[mt] = __builtin_amdgcn_mfma_f32_16x16x32_bf16(w1f[mt][0], hB, a1[mt], 0, 0, 0);
                a1[mt] = __builtin_amdgcn_mfma_f32_16x16x32_bf16(w1f[mt][1], xB, a1[mt], 0, 0, 0);
                a3[mt] = b3v[mt];
                a3[mt] = __builtin_amdgcn_mfma_f32_16x16x32_bf16(w3f[mt], hB, a3[mt], 0, 0, 0);
            }

            // ---- z = tanh(u1) packed per tile (pads are exactly 0) ----
            uint32_t zp[4][2];
#pragma unroll
            for (int mt = 0; mt < 4; ++mt) {
                zp[mt][0] = pack2(tanh_pre(a1[mt][0]), tanh_pre(a1[mt][1]));
                zp[mt][1] = pack2(tanh_pre(a1[mt][2]), tanh_pre(a1[mt][3]));
            }
            // ---- z transpose: zB0 (k 0..31, tiles 0/1), zB1 (k 32..63, tiles 2/3) ----
            uint4v z0d, z1d;
            z0d[0] = quad < 2 ? bperm(a_lo, zp[0][0]) : bperm(a_lo, zp[1][0]);
            z0d[1] = quad < 2 ? bperm(a_lo, zp[0][1]) : bperm(a_lo, zp[1][1]);
            z0d[2] = quad < 2 ? bperm(a_hi, zp[0][0]) : bperm(a_hi, zp[1][0]);
            z0d[3] = quad < 2 ? bperm(a_hi, zp[0][1]) : bperm(a_hi, zp[1][1]);
            z1d[0] = quad < 2 ? bperm(a_lo, zp[2][0]) : bperm(a_lo, zp[3][0]);
            z1d[1] = quad < 2 ? bperm(a_lo, zp[2][1]) : bperm(a_lo, zp[3][1]);
            z1d[2] = quad < 2 ? bperm(a_hi, zp[2][0]) : bperm(a_hi, zp[3][0]);
            z1d[3] = quad < 2 ? bperm(a_hi, zp[2][1]) : bperm(a_hi, zp[3][1]);
            short8 zB0 = __builtin_bit_cast(short8, z0d);
            short8 zB1 = __builtin_bit_cast(short8, z1d);

            // ---- u2 (4 MFMA) + h update ----
#pragma unroll
            for (int mt = 0; mt < 2; ++mt) {
                float4v u2 = b2v[mt];
                u2 = __builtin_amdgcn_mfma_f32_16x16x32_bf16(w2f[mt][0], zB0, u2, 0, 0, 0);
                u2 = __builtin_amdgcn_mfma_f32_16x16x32_bf16(w2f[mt][1], zB1, u2, 0, 0, 0);
                hC[mt][0] += s10 * tanh_pre(u2[0]);
                hC[mt][1] += s10 * tanh_pre(u2[1]);
                hC[mt][2] += s10 * tanh_pre(u2[2]);
                hC[mt][3] += s10 * tanh_pre(u2[3]);
            }

            // ---- dy partial (independent filler work; reduce deferred to per-t) ----
#pragma unroll
            for (int mt = 0; mt < 4; ++mt) {
                psum += w4v[mt][0] * tanh_pre(a3[mt][0]);
                psum += w4v[mt][1] * tanh_pre(a3[mt][1]);
                psum += w4v[mt][2] * tanh_pre(a3[mt][2]);
                psum += w4v[mt][3] * tanh_pre(a3[mt][3]);
            }
        } // euler

        // ---- finalize y for this t: one cross-quad reduce ----
        psum += __shfl_xor(psum, 16, 64);
        psum += __shfl_xor(psum, 32, 64);
        float y = y0 + STEPF * scl * (psum + (float)EULER * b4s);
        if (quad == 0)
            out[(size_t)(b0 + n16) * T_STEPS + t] = y;
    } // t
}

extern "C" void kernel_launch(void* const* d_in, const int* in_sizes, int n_in,
                              void* d_out, int out_size, void* d_ws, size_t ws_size,
                              hipStream_t stream) {
    const float* dt = (const float*)d_in[0];
    const float* x  = (const float*)d_in[1];
    const float* W1 = (const float*)d_in[2];
    const float* b1 = (const float*)d_in[3];
    const float* W2 = (const float*)d_in[4];
    const float* b2 = (const float*)d_in[5];
    const float* W3 = (const float*)d_in[6];
    const float* b3 = (const float*)d_in[7];
    const float* W4 = (const float*)d_in[8];
    const float* b4 = (const float*)d_in[9];
    float* out = (float*)d_out;

    const int B = 8192;
    dim3 grid(B / 16), block(64);
    latode_kernel<<<grid, block, 0, stream>>>(dt, x, W1, b1, W2, b2, W3, b3, W4, b4, out);
}

// Round 7
// 834.883 us; speedup vs baseline: 1.5836x; 1.5836x over previous
//
#include <hip/hip_runtime.h>
#include <stdint.h>

#define T_STEPS 100
#define D_IN 16
#define H_DIM 32
#define HD 50
#define KXH 48
#define EULER 10
#define STEPF 0.1f
#define DT_SCALERF (1.0f/24.0f)
#define TANH_SCALE 2.8853900817779268f   // 2*log2(e), folded into W1/W2/W3 + biases

typedef __attribute__((ext_vector_type(8))) short short8;
typedef __attribute__((ext_vector_type(4))) float float4v;
typedef __attribute__((ext_vector_type(4))) uint32_t uint4v;

// input prescaled by 2*log2(e): tanh(u) = 1 - 2/(exp2(us)+1)
__device__ __forceinline__ float tanh_pre(float us) {
    float e = __builtin_amdgcn_exp2f(us);
    return 1.0f - 2.0f * __builtin_amdgcn_rcpf(e + 1.0f);
}
__device__ __forceinline__ uint32_t f2bf_u(float f) {
    uint32_t u = __builtin_bit_cast(uint32_t, f);
    return u + 0x7fffu + ((u >> 16) & 1u);   // RNE
}
__device__ __forceinline__ uint32_t pack2(float lo, float hi) {
    return __builtin_amdgcn_perm(f2bf_u(hi), f2bf_u(lo), 0x07060302u);
}
__device__ __forceinline__ short f2bf(float f) { return (short)(f2bf_u(f) >> 16); }

// Permuted-feature formulation: h K-slot k holds semantic h-feat
//   pi(8q+j) = 16*(j>=4) + 4q + (j&3)
// and z K-slot (kt*32 + 8q+j) holds semantic z-feat kt*32 + 16*(j>=4) + 4q + (j&3).
// W1/W3 columns and W2 columns are permuted accordingly at load (free). With
// this basis, the C-layout regs each lane holds ARE the B-frag slots the same
// lane needs: activations move layer-to-layer with 4-8 v_perm packs and ZERO
// cross-lane / LDS / barrier traffic inside the h-recurrence.
//
// 2 waves per block (16 batch): wave 0 = h-recurrence (u1 -> z -> u2 -> h),
// publishes the 10 per-Euler hB frags of each t into parity-double-buffered
// LDS (fire-and-forget b128 writes); wave 1 = dy path (u3 + 16 tanh + reduce
// + y store), consuming a whole t after ONE barrier per t.
__global__ __launch_bounds__(128) void latode_kernel(
    const float* __restrict__ dt, const float* __restrict__ x,
    const float* __restrict__ W1, const float* __restrict__ b1,
    const float* __restrict__ W2, const float* __restrict__ b2,
    const float* __restrict__ W3, const float* __restrict__ b3,
    const float* __restrict__ W4, const float* __restrict__ b4,
    float* __restrict__ out)
{
    const int tid  = threadIdx.x;
    const int wave = tid >> 6;
    const int lane = tid & 63;
    const int n16  = lane & 15;       // batch column / weight out-feature row
    const int quad = lane >> 4;
    const int b0   = blockIdx.x * 16;

    // [parity][euler][lane*4 + w] packed-bf16 hB frags; 20.5 KB
    __shared__ __align__(16) uint32_t hbuf[2 * EULER * 256];

    const float b4s = b4[0];

    if (wave == 0) {
        // ======================= h-wave =======================
        // W1: rows raw (>=50 zeroed); h-cols permuted by pi, x-cols at slots 0..15 of kt=1
        short8 w1f[4][2];
#pragma unroll
        for (int mt = 0; mt < 4; ++mt) {
            int row = mt * 16 + n16;
#pragma unroll
            for (int j = 0; j < 8; ++j) {
                // kt=0: semantic h-feat
                int hf = 16 * (j >> 2) + 4 * quad + (j & 3);
                w1f[mt][0][j] = f2bf(row < HD ? W1[row * KXH + 16 + hf] * TANH_SCALE : 0.0f);
                // kt=1: x slots 0..15, pad above
                int s = 8 * quad + j;
                w1f[mt][1][j] = f2bf((row < HD && s < 16) ? W1[row * KXH + s] * TANH_SCALE : 0.0f);
            }
        }
        // W2: rows raw (32); cols permuted by tau over 64 slots (z-feats >=50 are zero)
        short8 w2f[2][2];
#pragma unroll
        for (int mt = 0; mt < 2; ++mt) {
            int row = mt * 16 + n16;
#pragma unroll
            for (int kt = 0; kt < 2; ++kt)
#pragma unroll
                for (int j = 0; j < 8; ++j) {
                    int zf = kt * 32 + 16 * (j >> 2) + 4 * quad + (j & 3);
                    w2f[mt][kt][j] = f2bf(zf < HD ? W2[row * HD + zf] * TANH_SCALE : 0.0f);
                }
        }
        float4v b1v[4], b2v[2];
#pragma unroll
        for (int mt = 0; mt < 4; ++mt)
#pragma unroll
            for (int r = 0; r < 4; ++r) {
                int f = mt * 16 + 4 * quad + r;
                b1v[mt][r] = (f < HD) ? b1[f] * TANH_SCALE : 0.0f;
            }
#pragma unroll
        for (int mt = 0; mt < 2; ++mt)
#pragma unroll
            for (int r = 0; r < 4; ++r)
                b2v[mt][r] = b2[mt * 16 + 4 * quad + r] * TANH_SCALE;

        // h state, semantic feat 16*mt + 4*quad + r at hC[mt][r]
        float4v hC[2];
        hC[0] = (float4v){0.f, 0.f, 0.f, 0.f};
        hC[1] = (float4v){0.f, 0.f, 0.f, 0.f};

        const float* xrow = x + (size_t)(b0 + n16) * (T_STEPS * D_IN);
        const float* drow = dt + (size_t)(b0 + n16) * (T_STEPS * 2);
        float4 xa = {0,0,0,0}, xb = {0,0,0,0};
        if (quad < 2) {
            xa = *(const float4*)(xrow + quad * 8);
            xb = *(const float4*)(xrow + quad * 8 + 4);
        }
        float2 dtv = *(const float2*)(drow);

#pragma unroll 1
        for (int t = 0; t < T_STEPS; ++t) {
            short8 xB = (short8){0,0,0,0,0,0,0,0};
            if (quad < 2) {
                uint4v xp;
                xp[0] = pack2(xa.x, xa.y); xp[1] = pack2(xa.z, xa.w);
                xp[2] = pack2(xb.x, xb.y); xp[3] = pack2(xb.z, xb.w);
                xB = __builtin_bit_cast(short8, xp);
            }
            const float s10 = STEPF * ((dtv.y - dtv.x) * DT_SCALERF);
            { // prefetch t+1
                int tn = (t + 1 < T_STEPS) ? t + 1 : (T_STEPS - 1);
                if (quad < 2) {
                    xa = *(const float4*)(xrow + tn * D_IN + quad * 8);
                    xb = *(const float4*)(xrow + tn * D_IN + quad * 8 + 4);
                }
                dtv = *(const float2*)(drow + tn * 2);
            }
            uint32_t* hslot = &hbuf[(t & 1) * (EULER * 256) + lane * 4];

#pragma unroll 2
            for (int e = 0; e < EULER; ++e) {
                // hB: 4 lane-local packs (permuted basis => no cross-lane)
                uint4v hd;
                hd[0] = pack2(hC[0][0], hC[0][1]);
                hd[1] = pack2(hC[0][2], hC[0][3]);
                hd[2] = pack2(hC[1][0], hC[1][1]);
                hd[3] = pack2(hC[1][2], hC[1][3]);
                *(uint4v*)(hslot + e * 256) = hd;   // publish for dy-wave (fire & forget)
                short8 hB = __builtin_bit_cast(short8, hd);

                // u1: 4 tiles x 2 K-MFMA
                float4v a1[4];
#pragma unroll
                for (int mt = 0; mt < 4; ++mt) {
                    a1[mt] = b1v[mt];
                    a1[mt] = __builtin_amdgcn_mfma_f32_16x16x32_bf16(w1f[mt][0], hB, a1[mt], 0, 0, 0);
                    a1[mt] = __builtin_amdgcn_mfma_f32_16x16x32_bf16(w1f[mt][1], xB, a1[mt], 0, 0, 0);
                }
                // z = tanh(u1), lane-local packs (tiles 0-2 full; tile 3 only feats 48,49)
                uint4v z0d, z1d;
                z0d[0] = pack2(tanh_pre(a1[0][0]), tanh_pre(a1[0][1]));
                z0d[1] = pack2(tanh_pre(a1[0][2]), tanh_pre(a1[0][3]));
                z0d[2] = pack2(tanh_pre(a1[1][0]), tanh_pre(a1[1][1]));
                z0d[3] = pack2(tanh_pre(a1[1][2]), tanh_pre(a1[1][3]));
                z1d[0] = pack2(tanh_pre(a1[2][0]), tanh_pre(a1[2][1]));
                z1d[1] = pack2(tanh_pre(a1[2][2]), tanh_pre(a1[2][3]));
                z1d[2] = (quad == 0) ? pack2(tanh_pre(a1[3][0]), tanh_pre(a1[3][1])) : 0u;
                z1d[3] = 0u;
                short8 zB0 = __builtin_bit_cast(short8, z0d);
                short8 zB1 = __builtin_bit_cast(short8, z1d);

                // u2: 2 tiles x 2 K-MFMA, then h update
#pragma unroll
                for (int mt = 0; mt < 2; ++mt) {
                    float4v u2 = b2v[mt];
                    u2 = __builtin_amdgcn_mfma_f32_16x16x32_bf16(w2f[mt][0], zB0, u2, 0, 0, 0);
                    u2 = __builtin_amdgcn_mfma_f32_16x16x32_bf16(w2f[mt][1], zB1, u2, 0, 0, 0);
                    hC[mt][0] += s10 * tanh_pre(u2[0]);
                    hC[mt][1] += s10 * tanh_pre(u2[1]);
                    hC[mt][2] += s10 * tanh_pre(u2[2]);
                    hC[mt][3] += s10 * tanh_pre(u2[3]);
                }
            } // e
            __syncthreads();   // t's 10 hB frags visible; pairs with dy-wave's t barrier
        } // t
    } else {
        // ======================= dy-wave =======================
        // W3: rows raw (64); cols permuted by pi
        short8 w3f[4];
        float4v b3v[4], w4v[4];
#pragma unroll
        for (int mt = 0; mt < 4; ++mt) {
            int row = mt * 16 + n16;
#pragma unroll
            for (int j = 0; j < 8; ++j) {
                int hf = 16 * (j >> 2) + 4 * quad + (j & 3);
                w3f[mt][j] = f2bf(W3[row * H_DIM + hf] * TANH_SCALE);
            }
#pragma unroll
            for (int r = 0; r < 4; ++r) {
                int f = mt * 16 + 4 * quad + r;
                b3v[mt][r] = b3[f] * TANH_SCALE;
                w4v[mt][r] = W4[f];
            }
        }
        const float* xrow = x + (size_t)(b0 + n16) * (T_STEPS * D_IN);
        const float* drow = dt + (size_t)(b0 + n16) * (T_STEPS * 2);
        float2 dtv = *(const float2*)(drow);
        float y0 = xrow[0];

#pragma unroll 1
        for (int t = 0; t < T_STEPS; ++t) {
            const float scl_c = (dtv.y - dtv.x) * DT_SCALERF;
            const float y0_c  = y0;
            { // prefetch t+1
                int tn = (t + 1 < T_STEPS) ? t + 1 : (T_STEPS - 1);
                dtv = *(const float2*)(drow + tn * 2);
                y0  = xrow[tn * D_IN];
            }
            __syncthreads();   // t's hB frags ready (pairs with h-wave end-of-t)

            const uint32_t* hslot = &hbuf[(t & 1) * (EULER * 256) + lane * 4];
            // load all 10 frags up front (latency pipelined)
            uint4v hds[EULER];
#pragma unroll
            for (int e = 0; e < EULER; ++e)
                hds[e] = *(const uint4v*)(hslot + e * 256);

            float psum = 0.0f;
#pragma unroll
            for (int e = 0; e < EULER; ++e) {
                short8 hB = __builtin_bit_cast(short8, hds[e]);
                float4v a3[4];
#pragma unroll
                for (int mt = 0; mt < 4; ++mt) {
                    a3[mt] = b3v[mt];
                    a3[mt] = __builtin_amdgcn_mfma_f32_16x16x32_bf16(w3f[mt], hB, a3[mt], 0, 0, 0);
                }
#pragma unroll
                for (int mt = 0; mt < 4; ++mt) {
                    psum += w4v[mt][0] * tanh_pre(a3[mt][0]);
                    psum += w4v[mt][1] * tanh_pre(a3[mt][1]);
                    psum += w4v[mt][2] * tanh_pre(a3[mt][2]);
                    psum += w4v[mt][3] * tanh_pre(a3[mt][3]);
                }
            }
            psum += __shfl_xor(psum, 16, 64);
            psum += __shfl_xor(psum, 32, 64);
            float y = y0_c + STEPF * scl_c * (psum + (float)EULER * b4s);
            if (quad == 0)
                out[(size_t)(b0 + n16) * T_STEPS + t] = y;
        } // t
    }
}

extern "C" void kernel_launch(void* const* d_in, const int* in_sizes, int n_in,
                              void* d_out, int out_size, void* d_ws, size_t ws_size,
                              hipStream_t stream) {
    const float* dt = (const float*)d_in[0];
    const float* x  = (const float*)d_in[1];
    const float* W1 = (const float*)d_in[2];
    const float* b1 = (const float*)d_in[3];
    const float* W2 = (const float*)d_in[4];
    const float* b2 = (const float*)d_in[5];
    const float* W3 = (const float*)d_in[6];
    const float* b3 = (const float*)d_in[7];
    const float* W4 = (const float*)d_in[8];
    const float* b4 = (const float*)d_in[9];
    float* out = (float*)d_out;

    const int B = 8192;
    dim3 grid(B / 16), block(128);
    latode_kernel<<<grid, block, 0, stream>>>(dt, x, W1, b1, W2, b2, W3, b3, W4, b4, out);
}

// Round 8
// 781.680 us; speedup vs baseline: 1.6914x; 1.0681x over previous
//
#include <hip/hip_runtime.h>
#include <stdint.h>

#define T_STEPS 100
#define D_IN 16
#define H_DIM 32
#define HD 50
#define KXH 48
#define EULER 10
#define STEPF 0.1f
#define DT_SCALERF (1.0f/24.0f)
#define TANH_SCALE 2.8853900817779268f   // 2*log2(e), folded into W1/W2/W3 + biases

typedef __attribute__((ext_vector_type(8))) short short8;
typedef __attribute__((ext_vector_type(4))) float float4v;
typedef __attribute__((ext_vector_type(4))) uint32_t uint4v;

// input prescaled by 2*log2(e): tanh(u) = 1 - 2/(exp2(us)+1)
__device__ __forceinline__ float tanh_pre(float us) {
    float e = __builtin_amdgcn_exp2f(us);
    return 1.0f - 2.0f * __builtin_amdgcn_rcpf(e + 1.0f);
}
// RNE bf16 (weights / setup only)
__device__ __forceinline__ uint32_t f2bf_u(float f) {
    uint32_t u = __builtin_bit_cast(uint32_t, f);
    return u + 0x7fffu + ((u >> 16) & 1u);
}
__device__ __forceinline__ short f2bf(float f) { return (short)(f2bf_u(f) >> 16); }
// TRUNCATION pack: single v_perm, no rounding (hot path; masters stay fp32)
__device__ __forceinline__ uint32_t pack2t(float lo, float hi) {
    return __builtin_amdgcn_perm(__builtin_bit_cast(uint32_t, hi),
                                 __builtin_bit_cast(uint32_t, lo), 0x07060302u);
}

// One fully self-contained wave per 16-batch chain: zero LDS, zero barriers,
// zero cross-lane ops in the Euler loop. Permuted-feature basis (verified
// R7: conflicts=0, absmax unchanged):
//   h K-slot 8q+j          holds semantic h-feat 16*(j>=4) + 4q + (j&3)
//   z K-slot kt*32+8q+j    holds semantic z-feat kt*32 + 16*(j>=4) + 4q + (j&3)
// With W1/W3/W2 columns permuted to match, the C-layout regs a lane holds ARE
// the B-frag dwords the same lane needs: layer-to-layer = 1 v_perm per pair.
// The dy path (u3 + 16 tanh + fma) is in-wave independent work that fills the
// h-chain's MFMA/transcendental latency stalls.
__global__ __launch_bounds__(64) void latode_kernel(
    const float* __restrict__ dt, const float* __restrict__ x,
    const float* __restrict__ W1, const float* __restrict__ b1,
    const float* __restrict__ W2, const float* __restrict__ b2,
    const float* __restrict__ W3, const float* __restrict__ b3,
    const float* __restrict__ W4, const float* __restrict__ b4,
    float* __restrict__ out)
{
    const int lane = threadIdx.x;
    const int n16  = lane & 15;       // batch column / weight out-feature row
    const int quad = lane >> 4;
    const int b0   = blockIdx.x * 16;

    // ---- constant weight A-frags (bf16 RNE, prescaled by 2*log2e) ----
    // W1: rows raw (>=50 zero); kt=0 h-cols permuted by pi; kt=1 x at slots 0..15
    short8 w1f[4][2];
#pragma unroll
    for (int mt = 0; mt < 4; ++mt) {
        int row = mt * 16 + n16;
#pragma unroll
        for (int j = 0; j < 8; ++j) {
            int hf = 16 * (j >> 2) + 4 * quad + (j & 3);
            w1f[mt][0][j] = f2bf(row < HD ? W1[row * KXH + 16 + hf] * TANH_SCALE : 0.0f);
            int s = 8 * quad + j;
            w1f[mt][1][j] = f2bf((row < HD && s < 16) ? W1[row * KXH + s] * TANH_SCALE : 0.0f);
        }
    }
    // W2: rows raw (32); cols permuted by tau over 64 slots (z-feats >=50 zero)
    short8 w2f[2][2];
#pragma unroll
    for (int mt = 0; mt < 2; ++mt) {
        int row = mt * 16 + n16;
#pragma unroll
        for (int kt = 0; kt < 2; ++kt)
#pragma unroll
            for (int j = 0; j < 8; ++j) {
                int zf = kt * 32 + 16 * (j >> 2) + 4 * quad + (j & 3);
                w2f[mt][kt][j] = f2bf(zf < HD ? W2[row * HD + zf] * TANH_SCALE : 0.0f);
            }
    }
    // W3: rows raw (64); h-cols permuted by pi
    short8 w3f[4];
#pragma unroll
    for (int mt = 0; mt < 4; ++mt) {
        int row = mt * 16 + n16;
#pragma unroll
        for (int j = 0; j < 8; ++j) {
            int hf = 16 * (j >> 2) + 4 * quad + (j & 3);
            w3f[mt][j] = f2bf(W3[row * H_DIM + hf] * TANH_SCALE);
        }
    }
    float4v b1v[4], b3v[4], w4v[4], b2v[2];
#pragma unroll
    for (int mt = 0; mt < 4; ++mt)
#pragma unroll
        for (int r = 0; r < 4; ++r) {
            int f = mt * 16 + 4 * quad + r;
            b1v[mt][r] = (f < HD) ? b1[f] * TANH_SCALE : 0.0f;
            b3v[mt][r] = b3[f] * TANH_SCALE;
            w4v[mt][r] = W4[f];
        }
#pragma unroll
    for (int mt = 0; mt < 2; ++mt)
#pragma unroll
        for (int r = 0; r < 4; ++r)
            b2v[mt][r] = b2[mt * 16 + 4 * quad + r] * TANH_SCALE;
    const float b4s = b4[0];

    // h state fp32, semantic feat 16*mt + 4*quad + r at hC[mt][r]
    float4v hC[2];
    hC[0] = (float4v){0.f, 0.f, 0.f, 0.f};
    hC[1] = (float4v){0.f, 0.f, 0.f, 0.f};

    const float* xrow = x + (size_t)(b0 + n16) * (T_STEPS * D_IN);
    const float* drow = dt + (size_t)(b0 + n16) * (T_STEPS * 2);
    float4 xa = {0,0,0,0}, xb = {0,0,0,0};
    if (quad < 2) {
        xa = *(const float4*)(xrow + quad * 8);
        xb = *(const float4*)(xrow + quad * 8 + 4);
    }
    float2 dtv = *(const float2*)(drow);

#pragma unroll 1
    for (int t = 0; t < T_STEPS; ++t) {
        // x B-frag (k' 32..47 at kt=1 slots 0..15 -> quads 0/1 carry x, 2/3 zero)
        short8 xB = (short8){0,0,0,0,0,0,0,0};
        if (quad < 2) {
            uint4v xp;
            xp[0] = pack2t(xa.x, xa.y); xp[1] = pack2t(xa.z, xa.w);
            xp[2] = pack2t(xb.x, xb.y); xp[3] = pack2t(xb.z, xb.w);
            xB = __builtin_bit_cast(short8, xp);
        }
        const float scl = (dtv.y - dtv.x) * DT_SCALERF;
        const float s10 = STEPF * scl;
        const float y0c = xa.x;    // valid on quad==0 lanes (= x[t][0]); only they store

        { // prefetch t+1
            int tn = (t + 1 < T_STEPS) ? t + 1 : (T_STEPS - 1);
            if (quad < 2) {
                xa = *(const float4*)(xrow + tn * D_IN + quad * 8);
                xb = *(const float4*)(xrow + tn * D_IN + quad * 8 + 4);
            }
            dtv = *(const float2*)(drow + tn * 2);
        }

        float psum = 0.0f;

#pragma unroll 2
        for (int e = 0; e < EULER; ++e) {
            // hB: 4 lane-local truncation packs (permuted basis)
            uint4v hd;
            hd[0] = pack2t(hC[0][0], hC[0][1]);
            hd[1] = pack2t(hC[0][2], hC[0][3]);
            hd[2] = pack2t(hC[1][0], hC[1][1]);
            hd[3] = pack2t(hC[1][2], hC[1][3]);
            short8 hB = __builtin_bit_cast(short8, hd);

            // u1 (8 MFMA) and u3 (4 MFMA) off the same hB
            float4v a1[4], a3[4];
#pragma unroll
            for (int mt = 0; mt < 4; ++mt) {
                a1[mt] = b1v[mt];
                a1[mt] = __builtin_amdgcn_mfma_f32_16x16x32_bf16(w1f[mt][0], hB, a1[mt], 0, 0, 0);
                a1[mt] = __builtin_amdgcn_mfma_f32_16x16x32_bf16(w1f[mt][1], xB, a1[mt], 0, 0, 0);
                a3[mt] = b3v[mt];
                a3[mt] = __builtin_amdgcn_mfma_f32_16x16x32_bf16(w3f[mt], hB, a3[mt], 0, 0, 0);
            }

            // z = tanh(u1), lane-local trunc packs (tiles 0-2 full; tile 3 feats 48,49)
            uint4v z0d, z1d;
            z0d[0] = pack2t(tanh_pre(a1[0][0]), tanh_pre(a1[0][1]));
            z0d[1] = pack2t(tanh_pre(a1[0][2]), tanh_pre(a1[0][3]));
            z0d[2] = pack2t(tanh_pre(a1[1][0]), tanh_pre(a1[1][1]));
            z0d[3] = pack2t(tanh_pre(a1[1][2]), tanh_pre(a1[1][3]));
            z1d[0] = pack2t(tanh_pre(a1[2][0]), tanh_pre(a1[2][1]));
            z1d[1] = pack2t(tanh_pre(a1[2][2]), tanh_pre(a1[2][3]));
            z1d[2] = (quad == 0) ? pack2t(tanh_pre(a1[3][0]), tanh_pre(a1[3][1])) : 0u;
            z1d[3] = 0u;
            short8 zB0 = __builtin_bit_cast(short8, z0d);
            short8 zB1 = __builtin_bit_cast(short8, z1d);

            // u2 (4 MFMA) + h update
#pragma unroll
            for (int mt = 0; mt < 2; ++mt) {
                float4v u2 = b2v[mt];
                u2 = __builtin_amdgcn_mfma_f32_16x16x32_bf16(w2f[mt][0], zB0, u2, 0, 0, 0);
                u2 = __builtin_amdgcn_mfma_f32_16x16x32_bf16(w2f[mt][1], zB1, u2, 0, 0, 0);
                hC[mt][0] += s10 * tanh_pre(u2[0]);
                hC[mt][1] += s10 * tanh_pre(u2[1]);
                hC[mt][2] += s10 * tanh_pre(u2[2]);
                hC[mt][3] += s10 * tanh_pre(u2[3]);
            }

            // dy path: independent in-wave filler (16 tanh + fma into psum)
#pragma unroll
            for (int mt = 0; mt < 4; ++mt) {
                psum += w4v[mt][0] * tanh_pre(a3[mt][0]);
                psum += w4v[mt][1] * tanh_pre(a3[mt][1]);
                psum += w4v[mt][2] * tanh_pre(a3[mt][2]);
                psum += w4v[mt][3] * tanh_pre(a3[mt][3]);
            }
        } // e

        // finalize y for this t (only cross-lane ops in the whole loop)
        psum += __shfl_xor(psum, 16, 64);
        psum += __shfl_xor(psum, 32, 64);
        if (quad == 0)
            out[(size_t)(b0 + n16) * T_STEPS + t] =
                y0c + STEPF * scl * (psum + (float)EULER * b4s);
    } // t
}

extern "C" void kernel_launch(void* const* d_in, const int* in_sizes, int n_in,
                              void* d_out, int out_size, void* d_ws, size_t ws_size,
                              hipStream_t stream) {
    const float* dt = (const float*)d_in[0];
    const float* x  = (const float*)d_in[1];
    const float* W1 = (const float*)d_in[2];
    const float* b1 = (const float*)d_in[3];
    const float* W2 = (const float*)d_in[4];
    const float* b2 = (const float*)d_in[5];
    const float* W3 = (const float*)d_in[6];
    const float* b3 = (const float*)d_in[7];
    const float* W4 = (const float*)d_in[8];
    const float* b4 = (const float*)d_in[9];
    float* out = (float*)d_out;

    const int B = 8192;
    dim3 grid(B / 16), block(64);
    latode_kernel<<<grid, block, 0, stream>>>(dt, x, W1, b1, W2, b2, W3, b3, W4, b4, out);
}

// Round 9
// 772.440 us; speedup vs baseline: 1.7116x; 1.0120x over previous
//
#include <hip/hip_runtime.h>
#include <stdint.h>

#define T_STEPS 100
#define D_IN 16
#define H_DIM 32
#define HD 50
#define KXH 48
#define EULER 10
#define STEPF 0.1f
#define DT_SCALERF (1.0f/24.0f)
#define TANH_SCALE 2.8853900817779268f   // 2*log2(e), folded into W1/W2/W3 + biases

typedef __attribute__((ext_vector_type(8))) short short8;
typedef __attribute__((ext_vector_type(4))) float float4v;
typedef __attribute__((ext_vector_type(4))) uint32_t uint4v;

// input prescaled by 2*log2(e): tanh(u) = 1 - 2/(exp2(us)+1)
__device__ __forceinline__ float tanh_pre(float us) {
    float e = __builtin_amdgcn_exp2f(us);
    return 1.0f - 2.0f * __builtin_amdgcn_rcpf(e + 1.0f);
}
// RNE bf16 (weights / setup only)
__device__ __forceinline__ uint32_t f2bf_u(float f) {
    uint32_t u = __builtin_bit_cast(uint32_t, f);
    return u + 0x7fffu + ((u >> 16) & 1u);
}
__device__ __forceinline__ short f2bf(float f) { return (short)(f2bf_u(f) >> 16); }
// truncation pack: single v_perm (hot path; fp32 masters keep full precision)
__device__ __forceinline__ uint32_t pack2t(float lo, float hi) {
    return __builtin_amdgcn_perm(__builtin_bit_cast(uint32_t, hi),
                                 __builtin_bit_cast(uint32_t, lo), 0x07060302u);
}

// One self-contained wave per 16-batch chain: zero LDS / barriers / cross-lane
// (except 2 shfl per t). Permuted-feature basis (R7-verified) makes all
// layer-to-layer layout transforms lane-local v_perm packs.
// R9: x-MFMA hoisted out of the Euler loop (xB const across e); dy path
// software-pipelined by one e-step (a3_prev) so its 16 independent tanh+fma
// fill the u1/u3 MFMA latency window; y finalization is lag-1 across t.
__global__ __launch_bounds__(64) void latode_kernel(
    const float* __restrict__ dt, const float* __restrict__ x,
    const float* __restrict__ W1, const float* __restrict__ b1,
    const float* __restrict__ W2, const float* __restrict__ b2,
    const float* __restrict__ W3, const float* __restrict__ b3,
    const float* __restrict__ W4, const float* __restrict__ b4,
    float* __restrict__ out)
{
    const int lane = threadIdx.x;
    const int n16  = lane & 15;       // batch column / weight out-feature row
    const int quad = lane >> 4;
    const int b0   = blockIdx.x * 16;

    // ---- constant weight A-frags (bf16 RNE, prescaled by 2*log2e) ----
    short8 w1h[4], w1x[4];   // W1 h-part (K=32, cols permuted by pi) and x-part
#pragma unroll
    for (int mt = 0; mt < 4; ++mt) {
        int row = mt * 16 + n16;
#pragma unroll
        for (int j = 0; j < 8; ++j) {
            int hf = 16 * (j >> 2) + 4 * quad + (j & 3);
            w1h[mt][j] = f2bf(row < HD ? W1[row * KXH + 16 + hf] * TANH_SCALE : 0.0f);
            int s = 8 * quad + j;
            w1x[mt][j] = f2bf((row < HD && s < 16) ? W1[row * KXH + s] * TANH_SCALE : 0.0f);
        }
    }
    short8 w2f[2][2];
#pragma unroll
    for (int mt = 0; mt < 2; ++mt) {
        int row = mt * 16 + n16;
#pragma unroll
        for (int kt = 0; kt < 2; ++kt)
#pragma unroll
            for (int j = 0; j < 8; ++j) {
                int zf = kt * 32 + 16 * (j >> 2) + 4 * quad + (j & 3);
                w2f[mt][kt][j] = f2bf(zf < HD ? W2[row * HD + zf] * TANH_SCALE : 0.0f);
            }
    }
    short8 w3f[4];
#pragma unroll
    for (int mt = 0; mt < 4; ++mt) {
        int row = mt * 16 + n16;
#pragma unroll
        for (int j = 0; j < 8; ++j) {
            int hf = 16 * (j >> 2) + 4 * quad + (j & 3);
            w3f[mt][j] = f2bf(W3[row * H_DIM + hf] * TANH_SCALE);
        }
    }
    float4v b1v[4], b3v[4], w4v[4], b2v[2];
#pragma unroll
    for (int mt = 0; mt < 4; ++mt)
#pragma unroll
        for (int r = 0; r < 4; ++r) {
            int f = mt * 16 + 4 * quad + r;
            b1v[mt][r] = (f < HD) ? b1[f] * TANH_SCALE : 0.0f;
            b3v[mt][r] = b3[f] * TANH_SCALE;
            w4v[mt][r] = W4[f];
        }
#pragma unroll
    for (int mt = 0; mt < 2; ++mt)
#pragma unroll
        for (int r = 0; r < 4; ++r)
            b2v[mt][r] = b2[mt * 16 + 4 * quad + r] * TANH_SCALE;
    const float b4s10 = (float)EULER * b4[0];

    // h state fp32, semantic feat 16*mt + 4*quad + r at hC[mt][r]
    float4v hC[2];
    hC[0] = (float4v){0.f, 0.f, 0.f, 0.f};
    hC[1] = (float4v){0.f, 0.f, 0.f, 0.f};

    const float* xrow = x + (size_t)(b0 + n16) * (T_STEPS * D_IN);
    const float* drow = dt + (size_t)(b0 + n16) * (T_STEPS * 2);
    float4 xa = {0,0,0,0}, xb = {0,0,0,0};
    if (quad < 2) {
        xa = *(const float4*)(xrow + quad * 8);
        xb = *(const float4*)(xrow + quad * 8 + 4);
    }
    float2 dtv = *(const float2*)(drow);

    // dy software-pipeline state (lag 1 in e)
    float4v a3p[4];                       // a3 of previous e-step; u3(h=0) = b3
#pragma unroll
    for (int mt = 0; mt < 4; ++mt) a3p[mt] = b3v[mt];
    float psum = 0.0f, prev_scl = 0.0f, prev_y0 = 0.0f;

#pragma unroll 1
    for (int t = 0; t < T_STEPS; ++t) {
        // x B-frag (kt=1 slots 0..15 -> quads 0/1 carry x, 2/3 zero)
        short8 xB = (short8){0,0,0,0,0,0,0,0};
        if (quad < 2) {
            uint4v xp;
            xp[0] = pack2t(xa.x, xa.y); xp[1] = pack2t(xa.z, xa.w);
            xp[2] = pack2t(xb.x, xb.y); xp[3] = pack2t(xb.z, xb.w);
            xB = __builtin_bit_cast(short8, xp);
        }
        const float scl = (dtv.y - dtv.x) * DT_SCALERF;
        const float s10 = STEPF * scl;
        const float y0c = xa.x;            // x[t][0] on quad==0 lanes

        // hoisted x-contribution to u1 (const across the 10 Euler steps)
        float4v a1x[4];
#pragma unroll
        for (int mt = 0; mt < 4; ++mt)
            a1x[mt] = __builtin_amdgcn_mfma_f32_16x16x32_bf16(w1x[mt], xB, b1v[mt], 0, 0, 0);

        { // prefetch t+1
            int tn = (t + 1 < T_STEPS) ? t + 1 : (T_STEPS - 1);
            if (quad < 2) {
                xa = *(const float4*)(xrow + tn * D_IN + quad * 8);
                xb = *(const float4*)(xrow + tn * D_IN + quad * 8 + 4);
            }
            dtv = *(const float2*)(drow + tn * 2);
        }

#pragma unroll 2
        for (int e = 0; e < EULER; ++e) {
            // hB: 4 lane-local truncation packs
            uint4v hd;
            hd[0] = pack2t(hC[0][0], hC[0][1]);
            hd[1] = pack2t(hC[0][2], hC[0][3]);
            hd[2] = pack2t(hC[1][0], hC[1][1]);
            hd[3] = pack2t(hC[1][2], hC[1][3]);
            short8 hB = __builtin_bit_cast(short8, hd);

            // u1 (4 MFMA, x part pre-folded) and u3 (4 MFMA)
            float4v a1[4], a3[4];
#pragma unroll
            for (int mt = 0; mt < 4; ++mt) {
                a1[mt] = __builtin_amdgcn_mfma_f32_16x16x32_bf16(w1h[mt], hB, a1x[mt], 0, 0, 0);
                a3[mt] = __builtin_amdgcn_mfma_f32_16x16x32_bf16(w3f[mt], hB, b3v[mt], 0, 0, 0);
            }

            // ---- dy on a3_prev: independent filler for the MFMA latency window ----
            float d = 0.0f;
#pragma unroll
            for (int mt = 0; mt < 4; ++mt) {
                d += w4v[mt][0] * tanh_pre(a3p[mt][0]);
                d += w4v[mt][1] * tanh_pre(a3p[mt][1]);
                d += w4v[mt][2] * tanh_pre(a3p[mt][2]);
                d += w4v[mt][3] * tanh_pre(a3p[mt][3]);
            }
            if (e == 0) {
                // d = dy(t-1, e=9): finalize y(t-1)
                float pt = psum + d;
                pt += __shfl_xor(pt, 16, 64);
                pt += __shfl_xor(pt, 32, 64);
                if (t > 0 && quad == 0)
                    out[(size_t)(b0 + n16) * T_STEPS + (t - 1)] =
                        prev_y0 + STEPF * prev_scl * (pt + b4s10);
                psum = 0.0f;
                prev_scl = scl;
                prev_y0 = y0c;
            } else {
                psum += d;
            }
#pragma unroll
            for (int mt = 0; mt < 4; ++mt) a3p[mt] = a3[mt];

            // ---- z = tanh(u1), lane-local packs ----
            uint4v z0d, z1d;
            z0d[0] = pack2t(tanh_pre(a1[0][0]), tanh_pre(a1[0][1]));
            z0d[1] = pack2t(tanh_pre(a1[0][2]), tanh_pre(a1[0][3]));
            z0d[2] = pack2t(tanh_pre(a1[1][0]), tanh_pre(a1[1][1]));
            z0d[3] = pack2t(tanh_pre(a1[1][2]), tanh_pre(a1[1][3]));
            z1d[0] = pack2t(tanh_pre(a1[2][0]), tanh_pre(a1[2][1]));
            z1d[1] = pack2t(tanh_pre(a1[2][2]), tanh_pre(a1[2][3]));
            z1d[2] = (quad == 0) ? pack2t(tanh_pre(a1[3][0]), tanh_pre(a1[3][1])) : 0u;
            z1d[3] = 0u;
            short8 zB0 = __builtin_bit_cast(short8, z0d);
            short8 zB1 = __builtin_bit_cast(short8, z1d);

            // ---- u2 (4 MFMA) + h update ----
#pragma unroll
            for (int mt = 0; mt < 2; ++mt) {
                float4v u2 = b2v[mt];
                u2 = __builtin_amdgcn_mfma_f32_16x16x32_bf16(w2f[mt][0], zB0, u2, 0, 0, 0);
                u2 = __builtin_amdgcn_mfma_f32_16x16x32_bf16(w2f[mt][1], zB1, u2, 0, 0, 0);
                hC[mt][0] += s10 * tanh_pre(u2[0]);
                hC[mt][1] += s10 * tanh_pre(u2[1]);
                hC[mt][2] += s10 * tanh_pre(u2[2]);
                hC[mt][3] += s10 * tanh_pre(u2[3]);
            }
        } // e
    } // t

    // drain: dy(t=99, e=9) and final y
    {
        float d = 0.0f;
#pragma unroll
        for (int mt = 0; mt < 4; ++mt) {
            d += w4v[mt][0] * tanh_pre(a3p[mt][0]);
            d += w4v[mt][1] * tanh_pre(a3p[mt][1]);
            d += w4v[mt][2] * tanh_pre(a3p[mt][2]);
            d += w4v[mt][3] * tanh_pre(a3p[mt][3]);
        }
        float pt = psum + d;
        pt += __shfl_xor(pt, 16, 64);
        pt += __shfl_xor(pt, 32, 64);
        if (quad == 0)
            out[(size_t)(b0 + n16) * T_STEPS + (T_STEPS - 1)] =
                prev_y0 + STEPF * prev_scl * (pt + b4s10);
    }
}

extern "C" void kernel_launch(void* const* d_in, const int* in_sizes, int n_in,
                              void* d_out, int out_size, void* d_ws, size_t ws_size,
                              hipStream_t stream) {
    const float* dt = (const float*)d_in[0];
    const float* x  = (const float*)d_in[1];
    const float* W1 = (const float*)d_in[2];
    const float* b1 = (const float*)d_in[3];
    const float* W2 = (const float*)d_in[4];
    const float* b2 = (const float*)d_in[5];
    const float* W3 = (const float*)d_in[6];
    const float* b3 = (const float*)d_in[7];
    const float* W4 = (const float*)d_in[8];
    const float* b4 = (const float*)d_in[9];
    float* out = (float*)d_out;

    const int B = 8192;
    dim3 grid(B / 16), block(64);
    latode_kernel<<<grid, block, 0, stream>>>(dt, x, W1, b1, W2, b2, W3, b3, W4, b4, out);
}